// Round 1
// baseline (98.772 us; speedup 1.0000x reference)
//
#include <hip/hip_runtime.h>

#define MARGIN 9.0f
#define NB 32      // batch
#define NE 100000  // entities
#define ND 64      // dim
#define BLOCK 256

__global__ __launch_bounds__(BLOCK) void transe_score_kernel(
    const int* __restrict__ sub, const int* __restrict__ rel,
    const float* __restrict__ emb_e, const float* __restrict__ emb_rel,
    float* __restrict__ out)
{
    __shared__ float q[NB][ND];   // 8 KB: q_b = emb_e[sub_b] + emb_rel[rel_b]
    __shared__ float qq[NB];      // |q_b|^2

    const int t = threadIdx.x;

    // Block prologue: build q cooperatively (2048 elements, 8 per thread).
    for (int i = t; i < NB * ND; i += BLOCK) {
        const int b = i >> 6, d = i & 63;
        q[b][d] = emb_e[(size_t)sub[b] * ND + d] + emb_rel[(size_t)rel[b] * ND + d];
    }
    __syncthreads();
    if (t < NB) {
        float s = 0.f;
#pragma unroll
        for (int d = 0; d < ND; ++d) { const float v = q[t][d]; s += v * v; }
        qq[t] = s;
    }
    __syncthreads();

    const int e = blockIdx.x * BLOCK + t;
    if (e >= NE) return;

    // Entity row into registers: 16 x float4 = 64 floats (256 B).
    float4 r[16];
    const float4* rp = (const float4*)(emb_e + (size_t)e * ND);
#pragma unroll
    for (int i = 0; i < 16; ++i) r[i] = rp[i];

    float rr = 0.f;
#pragma unroll
    for (int i = 0; i < 16; ++i)
        rr += r[i].x * r[i].x + r[i].y * r[i].y + r[i].z * r[i].z + r[i].w * r[i].w;

    // dist^2 = |q|^2 + |r|^2 - 2 q.r  (1 FMA per element instead of sub+FMA)
    for (int b = 0; b < NB; ++b) {
        float a0 = 0.f, a1 = 0.f, a2 = 0.f, a3 = 0.f;
#pragma unroll
        for (int i = 0; i < 16; ++i) {
            const float4 qv = *(const float4*)&q[b][4 * i];  // wave-uniform -> broadcast
            a0 += qv.x * r[i].x;
            a1 += qv.y * r[i].y;
            a2 += qv.z * r[i].z;
            a3 += qv.w * r[i].w;
        }
        const float dot = (a0 + a1) + (a2 + a3);
        float d2 = qq[b] + rr - 2.f * dot;
        d2 = fmaxf(d2, 0.f);  // guard tiny negative from cancellation
        out[(size_t)b * NE + e] = MARGIN - sqrtf(d2);
    }
}

extern "C" void kernel_launch(void* const* d_in, const int* in_sizes, int n_in,
                              void* d_out, int out_size, void* d_ws, size_t ws_size,
                              hipStream_t stream)
{
    const int*   sub     = (const int*)d_in[0];
    const int*   rel     = (const int*)d_in[1];
    const float* emb_e   = (const float*)d_in[2];
    const float* emb_rel = (const float*)d_in[3];
    float*       out     = (float*)d_out;

    const int grid = (NE + BLOCK - 1) / BLOCK;  // 391
    transe_score_kernel<<<grid, BLOCK, 0, stream>>>(sub, rel, emb_e, emb_rel, out);
}

// Round 2
// 96.760 us; speedup vs baseline: 1.0208x; 1.0208x over previous
//
#include <hip/hip_runtime.h>

#define MARGIN 9.0f
#define NB 32      // batch
#define NE 100000  // entities
#define ND 64      // dim
#define BLOCK 256
#define BSPLIT 2              // grid.y: split batch to double wave count
#define BPER (NB / BSPLIT)    // 16 b's per block

// Prep kernel (1 block): q[b][d] = emb_e[sub[b]][d] + emb_rel[rel[b]][d] -> ws[0..2047]
//                        qq[b]  = |q_b|^2                                -> ws[2048..2079]
__global__ __launch_bounds__(256) void transe_prep(
    const int* __restrict__ sub, const int* __restrict__ rel,
    const float* __restrict__ emb_e, const float* __restrict__ emb_rel,
    float* __restrict__ qws)
{
    __shared__ float qs[NB][ND];
    const int t = threadIdx.x;
    for (int i = t; i < NB * ND; i += 256) {
        const int b = i >> 6, d = i & 63;
        const float v = emb_e[(size_t)sub[b] * ND + d] + emb_rel[(size_t)rel[b] * ND + d];
        qs[b][d] = v;
        qws[i] = v;
    }
    __syncthreads();
    if (t < NB) {
        float s = 0.f;
#pragma unroll
        for (int d = 0; d < ND; ++d) { const float v = qs[t][d]; s += v * v; }
        qws[NB * ND + t] = s;
    }
}

// Score kernel: thread-per-entity; q via wave-uniform pointer -> scalar loads
// (s_load + v_fmac_f32 v,s,v). No LDS at all in the hot loop.
__global__ __launch_bounds__(BLOCK) void transe_score(
    const float* __restrict__ emb_e, const float* __restrict__ qws,
    float* __restrict__ out)
{
    int e = blockIdx.x * BLOCK + threadIdx.x;
    const bool valid = (e < NE);
    if (e >= NE) e = NE - 1;   // clamp: keep loads in-bounds, avoid divergence

    // Entity row -> 16 x float4 registers (256 B; lanes hit distinct lines but
    // every byte of each line is consumed across the i-unroll -> L1 absorbs).
    float4 r[16];
    const float4* rp = (const float4*)(emb_e + (size_t)e * ND);
#pragma unroll
    for (int i = 0; i < 16; ++i) r[i] = rp[i];

    float rr = 0.f;
#pragma unroll
    for (int i = 0; i < 16; ++i)
        rr += r[i].x * r[i].x + r[i].y * r[i].y + r[i].z * r[i].z + r[i].w * r[i].w;

    const int b0 = blockIdx.y * BPER;
#pragma unroll 4
    for (int bb = 0; bb < BPER; ++bb) {
        const int b = b0 + bb;
        const float* __restrict__ q = qws + b * ND;  // wave-uniform address
        float a0 = 0.f, a1 = 0.f, a2 = 0.f, a3 = 0.f;
#pragma unroll
        for (int i = 0; i < 16; ++i) {
            a0 = fmaf(q[4 * i + 0], r[i].x, a0);
            a1 = fmaf(q[4 * i + 1], r[i].y, a1);
            a2 = fmaf(q[4 * i + 2], r[i].z, a2);
            a3 = fmaf(q[4 * i + 3], r[i].w, a3);
        }
        const float dot = (a0 + a1) + (a2 + a3);
        float d2 = qws[NB * ND + b] + rr - 2.f * dot;   // |q|^2 + |r|^2 - 2 q.r
        d2 = fmaxf(d2, 0.f);
        if (valid) out[(size_t)b * NE + e] = MARGIN - sqrtf(d2);
    }
}

extern "C" void kernel_launch(void* const* d_in, const int* in_sizes, int n_in,
                              void* d_out, int out_size, void* d_ws, size_t ws_size,
                              hipStream_t stream)
{
    const int*   sub     = (const int*)d_in[0];
    const int*   rel     = (const int*)d_in[1];
    const float* emb_e   = (const float*)d_in[2];
    const float* emb_rel = (const float*)d_in[3];
    float*       out     = (float*)d_out;
    float*       qws     = (float*)d_ws;   // needs 2080 floats = 8.3 KB

    transe_prep<<<1, 256, 0, stream>>>(sub, rel, emb_e, emb_rel, qws);

    dim3 grid((NE + BLOCK - 1) / BLOCK, BSPLIT);  // 391 x 2
    transe_score<<<grid, BLOCK, 0, stream>>>(emb_e, qws, out);
}